// Round 5
// baseline (2693.951 us; speedup 1.0000x reference)
//
#include <hip/hip_runtime.h>

// ResFCEventuallyLayer — fp32 dtype-confirmation round (R4 structure, dtype swap only).
// Math (verified decode of the reference):
//   rs   = x @ W^T                       (einsum "bj,ij->bi"; W is [out,in] -> B^T-native)
//   out1 = relu(1 - beta + rs)
//   res  = relu(1 - (beta_res - (x + out1)))
//   LeakyReLU(res) == res  (res is a relu output, always >= 0)
// Inputs fp32 per the reference/harness contract; output fp32.
// Evidence: R4 (bf16 interpretation) produced NaN — exactly the signature of
// reading fp32 words as bf16 halves; valid bf16 inputs cannot NaN in R4's math.
//
// Construct discipline: ONLY constructs proven to compile+run in R4.
// No MFMA, no ext vectors, no compound literals, no launch_bounds, no int4,
// no restrict, no custom typedefs.

#define NDIM 4096

__global__ void ResFCEventuallyLayer_82205674045459_kernel(
    const float* X, const float* W,
    const float* Bp, const float* Br,
    float* out)
{
    // 64 rows x 16 k tiles, padded leading dim 17 to kill bank conflicts.
    __shared__ float sA[64 * 17];
    __shared__ float sB[64 * 17];

    const int tid = threadIdx.x;          // 0..255
    const int tm  = tid >> 4;             // 0..15 -> output rows tm*4..tm*4+3
    const int tn  = tid & 15;             // 0..15 -> output cols tn*4..tn*4+3
    const int bm0 = blockIdx.y * 64;
    const int bn0 = blockIdx.x * 64;

    float acc[4][4];
    for (int i = 0; i < 4; i++)
        for (int j = 0; j < 4; j++)
            acc[i][j] = 0.0f;

    for (int k0 = 0; k0 < NDIM; k0 += 16) {
        // Stage 64x16 of X and of W. Thread t covers flat elements 4t..4t+3:
        // row = e>>4, col = e&15.
        for (int e = tid * 4; e < tid * 4 + 4; e++) {
            const int row = e >> 4;
            const int col = e & 15;
            sA[row * 17 + col] = X[(size_t)(bm0 + row) * NDIM + k0 + col];
            sB[row * 17 + col] = W[(size_t)(bn0 + row) * NDIM + k0 + col];
        }
        __syncthreads();

        for (int k = 0; k < 16; k++) {
            float a0 = sA[(tm * 4 + 0) * 17 + k];
            float a1 = sA[(tm * 4 + 1) * 17 + k];
            float a2 = sA[(tm * 4 + 2) * 17 + k];
            float a3 = sA[(tm * 4 + 3) * 17 + k];
            float b0 = sB[(tn * 4 + 0) * 17 + k];
            float b1 = sB[(tn * 4 + 1) * 17 + k];
            float b2 = sB[(tn * 4 + 2) * 17 + k];
            float b3 = sB[(tn * 4 + 3) * 17 + k];
            acc[0][0] += a0 * b0; acc[0][1] += a0 * b1; acc[0][2] += a0 * b2; acc[0][3] += a0 * b3;
            acc[1][0] += a1 * b0; acc[1][1] += a1 * b1; acc[1][2] += a1 * b2; acc[1][3] += a1 * b3;
            acc[2][0] += a2 * b0; acc[2][1] += a2 * b1; acc[2][2] += a2 * b2; acc[2][3] += a2 * b3;
            acc[3][0] += a3 * b0; acc[3][1] += a3 * b1; acc[3][2] += a3 * b2; acc[3][3] += a3 * b3;
        }
        __syncthreads();
    }

    // Fused epilogue.
    const float one_m_beta = 1.0f - Bp[0];
    for (int i = 0; i < 4; i++) {
        const int m = bm0 + tm * 4 + i;
        for (int j = 0; j < 4; j++) {
            const int n = bn0 + tn * 4 + j;
            const size_t idx = (size_t)m * NDIM + n;
            float v = acc[i][j] + one_m_beta;
            if (v < 0.0f) v = 0.0f;                    // relu(1 - beta + rowsum)
            float res = 1.0f - Br[n] + X[idx] + v;
            if (res < 0.0f) res = 0.0f;                // relu; leaky on relu output == identity
            out[idx] = res;
        }
    }
}

extern "C" void kernel_launch(void* const* d_in, const int* in_sizes, int n_in,
                              void* d_out, int out_size, void* d_ws, size_t ws_size,
                              hipStream_t stream) {
    (void)in_sizes; (void)n_in; (void)out_size; (void)d_ws; (void)ws_size;

    const float* X  = (const float*)d_in[0];
    const float* W  = (const float*)d_in[1];
    const float* Bp = (const float*)d_in[2];
    const float* Br = (const float*)d_in[3];
    float* out      = (float*)d_out;

    dim3 grid(NDIM / 64, NDIM / 64);
    dim3 block(256);
    hipLaunchKernelGGL(ResFCEventuallyLayer_82205674045459_kernel,
                       grid, block, 0, stream, X, W, Bp, Br, out);
}

// Round 6
// 580.309 us; speedup vs baseline: 4.6423x; 4.6423x over previous
//
#include <hip/hip_runtime.h>

// ResFCEventuallyLayer — MFMA round (fp32 in/out, bf16 MFMA compute).
//   rs   = x @ W^T            (einsum "bj,ij->bi": both operands K-major = gemm_bt)
//   out1 = relu(1 - beta + rs)
//   res  = relu(1 - (beta_res - (x + out1)));  LeakyReLU(res>=0) == identity
//
// Structure: 128x128 tile, BK=32, 256 thr (4 waves 2x2), 4x4 accs of
// mfma_f32_16x16x32_bf16. fp32->bf16 RNE conversion fused into LDS staging.
// Construct discipline (R1-R3 compile-failure post-mortem): NO compound
// literals, no launch_bounds, no <<< >>>, no address-space casts; frag type
// __bf16 ext-vector per upstream builtin signature V4fV8yV8yV4f.

#define NDIM 4096

typedef __bf16 bf16x8 __attribute__((ext_vector_type(8)));
typedef float f32x4 __attribute__((ext_vector_type(4)));

__device__ unsigned short f2bf(float f) {
    unsigned int x;
    __builtin_memcpy(&x, &f, 4);
    unsigned int r = x + 0x7FFFu + ((x >> 16) & 1u);   // round-to-nearest-even
    return (unsigned short)(r >> 16);
}

__device__ unsigned int pack_bf2(float lo, float hi) {
    return (unsigned int)f2bf(lo) | ((unsigned int)f2bf(hi) << 16);
}

__global__ void ResFCEventuallyLayer_82205674045459_kernel(
    const float* X, const float* W,
    const float* Bp, const float* Br,
    float* out)
{
    // Tiles: 128 rows x 32 k of bf16 = 8 KB each, row stride 16 uints (64 B).
    __shared__ __align__(16) unsigned int sA[128 * 16];
    __shared__ __align__(16) unsigned int sB[128 * 16];

    const int t    = threadIdx.x;      // 0..255
    const int lane = t & 63;
    const int wave = t >> 6;           // 0..3
    const int quad = lane >> 4;        // 0..3
    const int l16  = lane & 15;
    const int wm   = wave >> 1;        // 0..1: 64-row half
    const int wn   = wave & 1;         // 0..1: 64-col half

    const int bm0 = blockIdx.y * 128;
    const int bn0 = blockIdx.x * 128;

    // Staging: per K-iter the tile is 128 rows x 8 float4-chunks = 1024 chunks.
    // Thread t handles chunks t+{0,256,512,768}: row = c>>3, col4 = c&7.
    const float* gA[4];
    const float* gB[4];
    int ldsIdx[4];
    for (int c = 0; c < 4; c++) {
        const int ch   = t + c * 256;
        const int row  = ch >> 3;
        const int col4 = ch & 7;
        gA[c] = X + (size_t)(bm0 + row) * NDIM + col4 * 4;
        gB[c] = W + (size_t)(bn0 + row) * NDIM + col4 * 4;
        ldsIdx[c] = row * 16 + col4 * 2;       // uint index; byte = row*64 + col4*8
    }

    // Fragment pointers. A-frag: lane holds A[m=l16][k=quad*8+j] -> 16 B at
    // LDS row (wm*64 + mt*16 + l16), byte offset quad*16. In bf16x8 units:
    // row*4 + quad; mt stride = 16 rows = 64 units. Same for B with wn.
    const bf16x8* pa = (const bf16x8*)sA + (wm * 64 + l16) * 4 + quad;
    const bf16x8* pb = (const bf16x8*)sB + (wn * 64 + l16) * 4 + quad;

    f32x4 acc[4][4];
    for (int i = 0; i < 4; i++)
        for (int j = 0; j < 4; j++)
            for (int r = 0; r < 4; r++)
                acc[i][j][r] = 0.0f;

    for (int k0 = 0; k0 < NDIM; k0 += 32) {
        // Global fp32 loads issued before the barrier (overlap prior MFMA).
        float4 va[4], vb[4];
        for (int c = 0; c < 4; c++) {
            va[c] = *(const float4*)(gA[c] + k0);
            vb[c] = *(const float4*)(gB[c] + k0);
        }
        __syncthreads();               // prior iteration's frag reads complete
        for (int c = 0; c < 4; c++) {
            uint2 ua, ub;
            ua.x = pack_bf2(va[c].x, va[c].y);
            ua.y = pack_bf2(va[c].z, va[c].w);
            ub.x = pack_bf2(vb[c].x, vb[c].y);
            ub.y = pack_bf2(vb[c].z, vb[c].w);
            *(uint2*)(sA + ldsIdx[c]) = ua;
            *(uint2*)(sB + ldsIdx[c]) = ub;
        }
        __syncthreads();               // tiles visible to all waves

        bf16x8 af[4], bfr[4];
        for (int mt = 0; mt < 4; mt++) af[mt]  = pa[mt * 64];
        for (int nt = 0; nt < 4; nt++) bfr[nt] = pb[nt * 64];

        for (int mt = 0; mt < 4; mt++)
            for (int nt = 0; nt < 4; nt++)
                acc[mt][nt] = __builtin_amdgcn_mfma_f32_16x16x32_bf16(
                    af[mt], bfr[nt], acc[mt][nt], 0, 0, 0);
    }

    // Fused epilogue. C/D layout: n(col) = lane&15, m(row) = quad*4 + reg.
    const float one_m_beta = 1.0f - Bp[0];
    for (int nt = 0; nt < 4; nt++) {
        const int n = bn0 + wn * 64 + nt * 16 + l16;
        const float br = Br[n];
        for (int mt = 0; mt < 4; mt++) {
            const int mbase = bm0 + wm * 64 + mt * 16 + quad * 4;
            for (int r = 0; r < 4; r++) {
                const size_t idx = (size_t)(mbase + r) * NDIM + n;
                float v = acc[mt][nt][r] + one_m_beta;
                if (v < 0.0f) v = 0.0f;                 // relu(1 - beta + rowsum)
                float res = 1.0f - br + X[idx] + v;
                if (res < 0.0f) res = 0.0f;             // relu; leaky on relu == id
                out[idx] = res;
            }
        }
    }
}

extern "C" void kernel_launch(void* const* d_in, const int* in_sizes, int n_in,
                              void* d_out, int out_size, void* d_ws, size_t ws_size,
                              hipStream_t stream) {
    (void)in_sizes; (void)n_in; (void)out_size; (void)d_ws; (void)ws_size;

    const float* X  = (const float*)d_in[0];
    const float* W  = (const float*)d_in[1];
    const float* Bp = (const float*)d_in[2];
    const float* Br = (const float*)d_in[3];
    float* out      = (float*)d_out;

    dim3 grid(NDIM / 128, NDIM / 128);
    dim3 block(256);
    hipLaunchKernelGGL(ResFCEventuallyLayer_82205674045459_kernel,
                       grid, block, 0, stream, X, W, Bp, Br, out);
}

// Round 7
// 348.080 us; speedup vs baseline: 7.7395x; 1.6672x over previous
//
#include <hip/hip_runtime.h>

// ResFCEventuallyLayer — two-phase: (1) fp32->bf16 pre-convert into d_ws,
// (2) pure-bf16 m93-style MFMA GEMM with fused epilogue.
//   rs   = x @ W^T            (einsum "bj,ij->bi": both operands K-major)
//   out1 = relu(1 - beta + rs)
//   res  = relu(1 - (beta_res - (x + out1)));  LeakyReLU(res>=0) == identity
// fp32 in/out; bf16 MFMA compute (absmax 2.0 vs threshold 7.32 proven in R6).
//
// Construct discipline (proven-in-R6 set only): ext vectors, MFMA builtin,
// scalar acc init, uint2/uint4 LDS stores, hipLaunchKernelGGL. No compound
// literals, no global_load_lds/AS casts (next round's single variable).

#define NDIM 4096

typedef __bf16 bf16x8 __attribute__((ext_vector_type(8)));
typedef float f32x4 __attribute__((ext_vector_type(4)));

__device__ unsigned short f2bf(float f) {
    unsigned int x;
    __builtin_memcpy(&x, &f, 4);
    unsigned int r = x + 0x7FFFu + ((x >> 16) & 1u);   // round-to-nearest-even
    return (unsigned short)(r >> 16);
}

__device__ unsigned int pack_bf2(float lo, float hi) {
    return (unsigned int)f2bf(lo) | ((unsigned int)f2bf(hi) << 16);
}

// Phase 1: fp32 -> packed bf16. 8 elements per thread.
__global__ void convert_f32_bf16_kernel(const float* src, unsigned int* dst) {
    const size_t i = ((size_t)blockIdx.x * blockDim.x + threadIdx.x) * 8;
    float4 v0 = *(const float4*)(src + i);
    float4 v1 = *(const float4*)(src + i + 4);
    uint4 u;
    u.x = pack_bf2(v0.x, v0.y);
    u.y = pack_bf2(v0.z, v0.w);
    u.z = pack_bf2(v1.x, v1.y);
    u.w = pack_bf2(v1.z, v1.w);
    *(uint4*)(dst + i / 2) = u;
}

// Phase 2: bf16-staged GEMM, 128x128 tile, BK=32, 4 waves 2x2, 4x4 accs.
__global__ void ResFCEventuallyLayer_82205674045459_kernel(
    const unsigned int* Xbf, const unsigned int* Wbf,
    const float* X, const float* Bp, const float* Br,
    float* out)
{
    // Tiles: 128 rows x 32 k of bf16 = 8 KB each; row = 64 B = 4 uint4 chunks.
    __shared__ __align__(16) unsigned int sA[128 * 16];
    __shared__ __align__(16) unsigned int sB[128 * 16];

    const int t    = threadIdx.x;      // 0..255
    const int lane = t & 63;
    const int wave = t >> 6;           // 0..3
    const int quad = lane >> 4;        // 0..3
    const int l16  = lane & 15;
    const int wm   = wave >> 1;        // 0..1: 64-row half
    const int wn   = wave & 1;         // 0..1: 64-col half

    const int bm0 = blockIdx.y * 128;
    const int bn0 = blockIdx.x * 128;

    // Staging: 512 x 16B chunks per tile; thread t handles chunks t and t+256.
    // Chunk c: row = c>>2, 16B-slot-in-row = c&3; LDS uint index = c*4.
    // Global row stride = 4096 bf16 = 512 uint4.
    const int c0 = t, c1 = t + 256;
    const uint4* gA0 = (const uint4*)Xbf + (size_t)(bm0 + (c0 >> 2)) * 512 + (c0 & 3);
    const uint4* gA1 = (const uint4*)Xbf + (size_t)(bm0 + (c1 >> 2)) * 512 + (c1 & 3);
    const uint4* gB0 = (const uint4*)Wbf + (size_t)(bn0 + (c0 >> 2)) * 512 + (c0 & 3);
    const uint4* gB1 = (const uint4*)Wbf + (size_t)(bn0 + (c1 >> 2)) * 512 + (c1 & 3);

    // Fragment pointers: lane holds A[m=l16][k=quad*8+j] -> 16 B at LDS row
    // (wm*64 + mt*16 + l16), byte offset quad*16. bf16x8 index = row*4 + quad.
    const bf16x8* pa = (const bf16x8*)sA + (wm * 64 + l16) * 4 + quad;
    const bf16x8* pb = (const bf16x8*)sB + (wn * 64 + l16) * 4 + quad;

    f32x4 acc[4][4];
    for (int i = 0; i < 4; i++)
        for (int j = 0; j < 4; j++)
            for (int r = 0; r < 4; r++)
                acc[i][j][r] = 0.0f;

    // 128 K-iterations; per iter the 32-k stripe = 4 uint4s per row.
    for (int s = 0; s < NDIM / 32; s++) {
        uint4 va0 = gA0[(size_t)s * 4];
        uint4 va1 = gA1[(size_t)s * 4];
        uint4 vb0 = gB0[(size_t)s * 4];
        uint4 vb1 = gB1[(size_t)s * 4];

        __syncthreads();               // prior iteration's frag reads complete
        *(uint4*)(sA + c0 * 4) = va0;
        *(uint4*)(sA + c1 * 4) = va1;
        *(uint4*)(sB + c0 * 4) = vb0;
        *(uint4*)(sB + c1 * 4) = vb1;
        __syncthreads();               // tiles visible to all waves

        bf16x8 af[4], bfr[4];
        for (int mt = 0; mt < 4; mt++) af[mt]  = pa[mt * 64];
        for (int nt = 0; nt < 4; nt++) bfr[nt] = pb[nt * 64];

        for (int mt = 0; mt < 4; mt++)
            for (int nt = 0; nt < 4; nt++)
                acc[mt][nt] = __builtin_amdgcn_mfma_f32_16x16x32_bf16(
                    af[mt], bfr[nt], acc[mt][nt], 0, 0, 0);
    }

    // Fused epilogue. C/D layout: n(col) = lane&15, m(row) = quad*4 + reg.
    const float one_m_beta = 1.0f - Bp[0];
    for (int nt = 0; nt < 4; nt++) {
        const int n = bn0 + wn * 64 + nt * 16 + l16;
        const float br = Br[n];
        for (int mt = 0; mt < 4; mt++) {
            const int mbase = bm0 + wm * 64 + mt * 16 + quad * 4;
            for (int r = 0; r < 4; r++) {
                const size_t idx = (size_t)(mbase + r) * NDIM + n;
                float v = acc[mt][nt][r] + one_m_beta;
                if (v < 0.0f) v = 0.0f;                 // relu(1 - beta + rowsum)
                float res = 1.0f - br + X[idx] + v;
                if (res < 0.0f) res = 0.0f;             // relu; leaky on relu == id
                out[idx] = res;
            }
        }
    }
}

// Fallback (R6 kernel, proven): in-loop conversion, no workspace needed.
__global__ void resfc_fallback_kernel(
    const float* X, const float* W,
    const float* Bp, const float* Br,
    float* out)
{
    __shared__ __align__(16) unsigned int sA[128 * 16];
    __shared__ __align__(16) unsigned int sB[128 * 16];

    const int t    = threadIdx.x;
    const int lane = t & 63;
    const int wave = t >> 6;
    const int quad = lane >> 4;
    const int l16  = lane & 15;
    const int wm   = wave >> 1;
    const int wn   = wave & 1;

    const int bm0 = blockIdx.y * 128;
    const int bn0 = blockIdx.x * 128;

    const float* gA[4];
    const float* gB[4];
    int ldsIdx[4];
    for (int c = 0; c < 4; c++) {
        const int ch   = t + c * 256;
        const int row  = ch >> 3;
        const int col4 = ch & 7;
        gA[c] = X + (size_t)(bm0 + row) * NDIM + col4 * 4;
        gB[c] = W + (size_t)(bn0 + row) * NDIM + col4 * 4;
        ldsIdx[c] = row * 16 + col4 * 2;
    }

    const bf16x8* pa = (const bf16x8*)sA + (wm * 64 + l16) * 4 + quad;
    const bf16x8* pb = (const bf16x8*)sB + (wn * 64 + l16) * 4 + quad;

    f32x4 acc[4][4];
    for (int i = 0; i < 4; i++)
        for (int j = 0; j < 4; j++)
            for (int r = 0; r < 4; r++)
                acc[i][j][r] = 0.0f;

    for (int k0 = 0; k0 < NDIM; k0 += 32) {
        float4 va[4], vb[4];
        for (int c = 0; c < 4; c++) {
            va[c] = *(const float4*)(gA[c] + k0);
            vb[c] = *(const float4*)(gB[c] + k0);
        }
        __syncthreads();
        for (int c = 0; c < 4; c++) {
            uint2 ua, ub;
            ua.x = pack_bf2(va[c].x, va[c].y);
            ua.y = pack_bf2(va[c].z, va[c].w);
            ub.x = pack_bf2(vb[c].x, vb[c].y);
            ub.y = pack_bf2(vb[c].z, vb[c].w);
            *(uint2*)(sA + ldsIdx[c]) = ua;
            *(uint2*)(sB + ldsIdx[c]) = ub;
        }
        __syncthreads();

        bf16x8 af[4], bfr[4];
        for (int mt = 0; mt < 4; mt++) af[mt]  = pa[mt * 64];
        for (int nt = 0; nt < 4; nt++) bfr[nt] = pb[nt * 64];

        for (int mt = 0; mt < 4; mt++)
            for (int nt = 0; nt < 4; nt++)
                acc[mt][nt] = __builtin_amdgcn_mfma_f32_16x16x32_bf16(
                    af[mt], bfr[nt], acc[mt][nt], 0, 0, 0);
    }

    const float one_m_beta = 1.0f - Bp[0];
    for (int nt = 0; nt < 4; nt++) {
        const int n = bn0 + wn * 64 + nt * 16 + l16;
        const float br = Br[n];
        for (int mt = 0; mt < 4; mt++) {
            const int mbase = bm0 + wm * 64 + mt * 16 + quad * 4;
            for (int r = 0; r < 4; r++) {
                const size_t idx = (size_t)(mbase + r) * NDIM + n;
                float v = acc[mt][nt][r] + one_m_beta;
                if (v < 0.0f) v = 0.0f;
                float res = 1.0f - br + X[idx] + v;
                if (res < 0.0f) res = 0.0f;
                out[idx] = res;
            }
        }
    }
}

extern "C" void kernel_launch(void* const* d_in, const int* in_sizes, int n_in,
                              void* d_out, int out_size, void* d_ws, size_t ws_size,
                              hipStream_t stream) {
    (void)in_sizes; (void)n_in; (void)out_size;

    const float* X  = (const float*)d_in[0];
    const float* W  = (const float*)d_in[1];
    const float* Bp = (const float*)d_in[2];
    const float* Br = (const float*)d_in[3];
    float* out      = (float*)d_out;

    const size_t elems   = (size_t)NDIM * NDIM;          // 16.7M per matrix
    const size_t bf_need = elems * 2 * 2;                // Xbf + Wbf, 2 B each

    dim3 gemm_grid(NDIM / 128, NDIM / 128);
    dim3 block(256);

    if (ws_size >= bf_need) {
        unsigned int* Xbf = (unsigned int*)d_ws;
        unsigned int* Wbf = (unsigned int*)d_ws + elems / 2;   // uint = 2 bf16

        dim3 cvt_grid((unsigned int)(elems / 8 / 256));
        hipLaunchKernelGGL(convert_f32_bf16_kernel, cvt_grid, block, 0, stream, X, Xbf);
        hipLaunchKernelGGL(convert_f32_bf16_kernel, cvt_grid, block, 0, stream, W, Wbf);
        hipLaunchKernelGGL(ResFCEventuallyLayer_82205674045459_kernel,
                           gemm_grid, block, 0, stream, Xbf, Wbf, X, Bp, Br, out);
    } else {
        hipLaunchKernelGGL(resfc_fallback_kernel,
                           gemm_grid, block, 0, stream, X, W, Bp, Br, out);
    }
}